// Round 12
// baseline (203.110 us; speedup 1.0000x reference)
//
#include <hip/hip_runtime.h>

// DBSCAN neighbor-count + classify via augmented-K bf16 MFMA, MI355X (gfx950)
// B=4, N=8192, D=16 fp32 in, int32 out.
// dist(i,j) < EPS=0.5  <=>  x_i.x_j - g_i - g_j > 0,  g_p = 0.5*||x_p||^2 - EPS^2/4
// Augmented point (24 bf16 = 48 B): [x0..x15, 1.0, -g, 0...]
//   A row i swaps k16..17 to [-g_i, 1]; B col j supplies [1, -g_j]
//   => mfma_f32_16x16x32_bf16 with zero C emits x_i.x_j - g_i - g_j directly.
// out[p] = (count_p < 10) ? -1 : 0
//
// R12: symmetry halving (R11) with ZERO global atomics. R11's counters showed
// the 2.6M in-loop device atomics generated ~476 MB of coherence traffic and
// serialized the kernel (VALUBusy 7%). Column counts now accumulate in LDS
// (LDS atomics) and are stored once per block to partC; row counts stored
// once per lane to partR; reduce kernel sums <=32 coalesced partials per
// point (row path for cj>=c, col path for ci<c) and fuses classification.

constexpr int Np = 8192;
constexpr int Bb = 4;
constexpr int MIN_PTS = 10;
constexpr float EPS2_4 = 0.0625f;  // EPS^2 / 4
constexpr int CH = 256;        // chunk edge (i-rows and j-cols per block)
constexpr int NC = Np / CH;    // 32 chunks per batch
constexpr int NT = CH / 16;    // 16 j-tiles per window
constexpr int RF = 4;          // A fragments per wave (16 rows each)

typedef __bf16 bf16x8 __attribute__((ext_vector_type(8)));
typedef float  f32x4  __attribute__((ext_vector_type(4)));

// ---------------- prep: fp32 -> augmented bf16 ------------------------------
__global__ __launch_bounds__(256)
void dbscan_prep(const float* __restrict__ x, __bf16* __restrict__ aug) {
    const int p = blockIdx.x * 256 + threadIdx.x;    // 32768 points
    const float4* src = (const float4*)(x + (size_t)p * 16);
    float4 v0 = src[0], v1 = src[1], v2 = src[2], v3 = src[3];
    float vv[16];
    vv[0]=v0.x; vv[1]=v0.y; vv[2]=v0.z; vv[3]=v0.w;
    vv[4]=v1.x; vv[5]=v1.y; vv[6]=v1.z; vv[7]=v1.w;
    vv[8]=v2.x; vv[9]=v2.y; vv[10]=v2.z; vv[11]=v2.w;
    vv[12]=v3.x; vv[13]=v3.y; vv[14]=v3.z; vv[15]=v3.w;
    float s = 0.f;
#pragma unroll
    for (int k = 0; k < 16; k++) s = fmaf(vv[k], vv[k], s);
    const float g = 0.5f * s - EPS2_4;
    bf16x8 h0, h1, h2;
#pragma unroll
    for (int k = 0; k < 8; k++) { h0[k] = (__bf16)vv[k]; h1[k] = (__bf16)vv[k+8]; }
    h2[0] = (__bf16)1.0f; h2[1] = (__bf16)(-g);
#pragma unroll
    for (int k = 2; k < 8; k++) h2[k] = (__bf16)0.0f;
    bf16x8* dst = (bf16x8*)(aug + (size_t)p * 24);
    dst[0] = h0; dst[1] = h1; dst[2] = h2;
}

// ---------------- count: triangular chunk sweep, partial stores -------------
// grid: 4 b x 32 ci x 32 cj = 4096 blocks (ci>cj exit), 256 threads (4 waves).
__global__ __launch_bounds__(256, 4)
void dbscan_count(const __bf16* __restrict__ aug,
                  int* __restrict__ partR, int* __restrict__ partC) {
    const int blk = blockIdx.x;
    const int b   = blk >> 10;
    const int ci  = (blk >> 5) & 31;
    const int cj  = blk & 31;
    if (ci > cj) return;                  // lower triangle covered by symmetry
    const bool diag = (ci == cj);

    const int lane = threadIdx.x & 63;
    const int w    = threadIdx.x >> 6;
    const int m    = lane & 15;          // A/B row-col within tile
    const int q    = lane >> 4;          // k-chunk; C row group
    const size_t pbase = (size_t)b * Np;
    const int ibase = ci * CH;
    const int jbase = cj * CH;
    const size_t pairOff = (size_t)((b * NC + ci) * NC + cj) * CH;

    // LDS j-window: [tile][slot], slot = r*16 + (p&15), 8 bf16/slot. 12.3 KB.
    __shared__ __bf16 ldsB[NT * 48 * 8];
    __shared__ int colLds[CH];           // column negative-sums (1 KB)

    colLds[threadIdx.x] = 0;

    // Stage 256 pts = 768 16B-chunks; chunk c = point p=c/3, piece r=c%3.
    {
        const __bf16* src = aug + (pbase + jbase) * 24;
#pragma unroll
        for (int it = 0; it < 3; it++) {
            const int c = threadIdx.x + it * 256;
            const int p = c / 3;
            const int r = c - p * 3;
            bf16x8 v = *(const bf16x8*)(src + (size_t)c * 8);
            *(bf16x8*)(ldsB + (((p >> 4) * 48) + r * 16 + (p & 15)) * 8) = v;
        }
    }

    // A fragments (loop-invariant). Rows: ibase + w*64 + f*16 + m.
    bf16x8 af[RF];
#pragma unroll
    for (int f = 0; f < RF; f++) {
        const __bf16* ap = aug + (pbase + ibase + w * 64 + f * 16 + m) * 24 + q * 8;
        bf16x8 a = *(const bf16x8*)ap;     // q=3 overreads next point; zeroed below
        if (q == 2) { __bf16 t = a[0]; a[0] = a[1]; a[1] = t; }   // [1,-g] -> [-g,1]
        if (q == 3) {
#pragma unroll
            for (int k = 0; k < 8; k++) a[k] = (__bf16)0.0f;
        }
        af[f] = a;
    }

    __syncthreads();

    // B fragment address: q<3 -> slot q*16+m; q==3 -> broadcast slot 0 (dead input)
    const __bf16* bptr = ldsB + (q < 3 ? (q * 16 + m) * 8 : 0);

    const f32x4 zacc = {0.f, 0.f, 0.f, 0.f};
    int rcnt[16];
#pragma unroll
    for (int i = 0; i < 16; i++) rcnt[i] = 0;

    bf16x8 bc = *(const bf16x8*)bptr;
#pragma unroll
    for (int t = 0; t < NT; t++) {
        bf16x8 bn = *(const bf16x8*)(bptr + ((t + 1) & (NT - 1)) * 48 * 8);
        int csum = 0;
#pragma unroll
        for (int f = 0; f < RF; f++) {
            f32x4 acc = __builtin_amdgcn_mfma_f32_16x16x32_bf16(af[f], bc, zacc, 0, 0, 0);
            const int s0 = __float_as_int(acc[0]) >> 31;   // -1 if negative
            const int s1 = __float_as_int(acc[1]) >> 31;
            const int s2 = __float_as_int(acc[2]) >> 31;
            const int s3 = __float_as_int(acc[3]) >> 31;
            rcnt[f*4+0] += s0; rcnt[f*4+1] += s1;
            rcnt[f*4+2] += s2; rcnt[f*4+3] += s3;
            csum += s0 + s1 + s2 + s3;
        }
        // column sum for this tile over the wave's 64 rows (lane bits 4,5)
        csum += __shfl_xor(csum, 16);
        csum += __shfl_xor(csum, 32);
        if (!diag && q == 0)
            atomicAdd(&colLds[t * 16 + m], csum);   // LDS atomic, cheap
        bc = bn;
    }

    // Row totals: sum across 16 cols (lane bits 0..3); value uniform in m.
#pragma unroll
    for (int i = 0; i < 16; i++) {
        int v = rcnt[i];
        v += __shfl_xor(v, 1);
        v += __shfl_xor(v, 2);
        v += __shfl_xor(v, 4);
        v += __shfl_xor(v, 8);
        rcnt[i] = v;
    }
    // Lane (m,q) stores row w*64 + (m>>2)*16 + q*4 + (m&3): one store/thread.
    {
        const int f = m >> 2, r = m & 3;
        partR[pairOff + w * 64 + f * 16 + q * 4 + r] = CH + rcnt[f * 4 + r];
    }
    // Column partials: one store/thread after all waves' LDS adds complete.
    __syncthreads();
    if (!diag)
        partC[pairOff + threadIdx.x] = CH + colLds[threadIdx.x];
}

// ---------------- reduce + classify -----------------------------------------
// 128 blocks x 256 threads; block covers one (b, c) window, thread = idx.
__global__ __launch_bounds__(256)
void dbscan_reduce(const int* __restrict__ partR, const int* __restrict__ partC,
                   int* __restrict__ out) {
    const int row = blockIdx.x * 256 + threadIdx.x;   // 32768 points
    const int b   = row >> 13;
    const int c   = (row >> 8) & 31;
    const int idx = row & 255;
    int s = 0;
    for (int cj = c; cj < NC; cj++)                    // row path (cj >= c)
        s += partR[(size_t)((b * NC + c) * NC + cj) * CH + idx];
    for (int ci = 0; ci < c; ci++)                     // col path (ci < c)
        s += partC[(size_t)((b * NC + ci) * NC + c) * CH + idx];
    out[row] = (s < MIN_PTS) ? -1 : 0;
}

extern "C" void kernel_launch(void* const* d_in, const int* in_sizes, int n_in,
                              void* d_out, int out_size, void* d_ws, size_t ws_size,
                              hipStream_t stream) {
    const float* x = (const float*)d_in[0];
    int* out = (int*)d_out;
    __bf16* aug = (__bf16*)d_ws;                        // 1.5 MB (+pad)
    int* partR  = (int*)((char*)d_ws + (2u << 20));     // 4 MB (4*32*32*256*4)
    int* partC  = (int*)((char*)d_ws + (6u << 20));     // 4 MB

    dbscan_prep<<<dim3(Bb * Np / 256), dim3(256), 0, stream>>>(x, aug);
    dbscan_count<<<dim3(Bb * NC * NC), dim3(256), 0, stream>>>(aug, partR, partC);
    dbscan_reduce<<<dim3(Bb * Np / 256), dim3(256), 0, stream>>>(partR, partC, out);
}

// Round 13
// 76.279 us; speedup vs baseline: 2.6627x; 2.6627x over previous
//
#include <hip/hip_runtime.h>

// DBSCAN neighbor-count + classify via augmented-K bf16 MFMA, MI355X (gfx950)
// B=4, N=8192, D=16 fp32 in, int32 out.
// dist(i,j) < EPS=0.5  <=>  x_i.x_j - g_i - g_j > 0,  g_p = 0.5*||x_p||^2 - EPS^2/4
// Augmented point (24 bf16 = 48 B): [x0..x15, 1.0, -g, 0...]
//   A row i swaps k16..17 to [-g_i, 1]; B col j supplies [1, -g_j]
//   => mfma_f32_16x16x32_bf16 with zero C emits x_i.x_j - g_i - g_j directly.
// out[p] = (count_p < 10) ? -1 : 0
//
// R13 = exact revert to R9, the measured best (76.4 us). R11/R12 proved the
// triangular halving is structurally HBM-bound under this harness (poison
// fill flushes all caches every launch; per-block locality dominates): count
// went 24.5 -> 141 us on ~480 MB of line-granular traffic despite half the
// MFMA work. R3-R10 falsified every scheduling lever beyond the sign-bit
// epilogue (R9, -4.3us, predicted). This structure is the plateau:
// fill+restore ~43 us fixed, prep/count/classify ~33 us, each fusion or
// restructure attempt measured neutral-to-worse.

constexpr int Np = 8192;
constexpr int Bb = 4;
constexpr int MIN_PTS = 10;
constexpr float EPS2_4 = 0.0625f;  // EPS^2 / 4
constexpr int JS = 16;         // j-windows per batch
constexpr int JW = Np / JS;    // 512 j per window/block
constexpr int ICH = 256;       // i rows per block (4 waves x 64)
constexpr int RF = 4;          // A fragments per wave (16 rows each)
constexpr int NT = JW / 16;    // 32 j-tiles per window

typedef __bf16 bf16x8 __attribute__((ext_vector_type(8)));
typedef float  f32x4  __attribute__((ext_vector_type(4)));

// ---------------- prep: fp32 -> augmented bf16; zero the count buffer -------
__global__ __launch_bounds__(256)
void dbscan_prep(const float* __restrict__ x, __bf16* __restrict__ aug,
                 int* __restrict__ out) {
    const int p = blockIdx.x * 256 + threadIdx.x;    // 32768 points
    const float4* src = (const float4*)(x + (size_t)p * 16);
    float4 v0 = src[0], v1 = src[1], v2 = src[2], v3 = src[3];
    float vv[16];
    vv[0]=v0.x; vv[1]=v0.y; vv[2]=v0.z; vv[3]=v0.w;
    vv[4]=v1.x; vv[5]=v1.y; vv[6]=v1.z; vv[7]=v1.w;
    vv[8]=v2.x; vv[9]=v2.y; vv[10]=v2.z; vv[11]=v2.w;
    vv[12]=v3.x; vv[13]=v3.y; vv[14]=v3.z; vv[15]=v3.w;
    float s = 0.f;
#pragma unroll
    for (int k = 0; k < 16; k++) s = fmaf(vv[k], vv[k], s);
    const float g = 0.5f * s - EPS2_4;
    bf16x8 h0, h1, h2;
#pragma unroll
    for (int k = 0; k < 8; k++) { h0[k] = (__bf16)vv[k]; h1[k] = (__bf16)vv[k+8]; }
    h2[0] = (__bf16)1.0f; h2[1] = (__bf16)(-g);
#pragma unroll
    for (int k = 2; k < 8; k++) h2[k] = (__bf16)0.0f;
    bf16x8* dst = (bf16x8*)(aug + (size_t)p * 24);
    dst[0] = h0; dst[1] = h1; dst[2] = h2;
    out[p] = 0;
}

// ---------------- count: LDS-staged Gram sweep, atomicAdd partials ----------
// grid: 4 b x 32 i-chunks x 16 j-windows = 2048 blocks, 256 threads.
__global__ __launch_bounds__(256, 6)
void dbscan_count(const __bf16* __restrict__ aug, int* __restrict__ out) {
    const int lane = threadIdx.x & 63;
    const int w    = threadIdx.x >> 6;
    const int m    = lane & 15;          // A/B row-col within tile
    const int q    = lane >> 4;          // k-chunk; C row group
    const int blk  = blockIdx.x;
    const int b    = blk >> 9;
    const int ic   = (blk >> 4) & 31;
    const int js   = blk & 15;
    const size_t pbase = (size_t)b * Np;
    const int ibase = ic * ICH;
    const int jbase = js * JW;

    // LDS: [tile][slot], slot = r*16 + (p&15), 8 bf16 per slot. 24.6 KB.
    __shared__ __bf16 ldsB[NT * 48 * 8];

    // Stage window: 1536 16B-chunks; chunk c = point p=c/3, piece r=c%3.
    {
        const __bf16* src = aug + (pbase + jbase) * 24;
#pragma unroll
        for (int it = 0; it < 6; it++) {
            const int c = threadIdx.x + it * 256;
            const int p = c / 3;
            const int r = c - p * 3;
            bf16x8 v = *(const bf16x8*)(src + (size_t)c * 8);
            *(bf16x8*)(ldsB + (((p >> 4) * 48) + r * 16 + (p & 15)) * 8) = v;
        }
    }

    // A fragments (global, loop-invariant). Rows: ibase+w*64+f*16+m.
    bf16x8 af[RF];
#pragma unroll
    for (int f = 0; f < RF; f++) {
        const __bf16* ap = aug + (pbase + ibase + w * 64 + f * 16 + m) * 24 + q * 8;
        bf16x8 a = *(const bf16x8*)ap;     // q=3 overreads next point; zeroed below
        if (q == 2) { __bf16 t = a[0]; a[0] = a[1]; a[1] = t; }   // [1,-g] -> [-g,1]
        if (q == 3) {
#pragma unroll
            for (int k = 0; k < 8; k++) a[k] = (__bf16)0.0f;
        }
        af[f] = a;
    }

    __syncthreads();

    // B fragment address: q<3 -> slot q*16+m; q==3 -> broadcast slot 0 (dead input)
    const __bf16* bptr = ldsB + (q < 3 ? (q * 16 + m) * 8 : 0);

    const f32x4 zacc = {0.f, 0.f, 0.f, 0.f};
    int cnt[16];
#pragma unroll
    for (int i = 0; i < 16; i++) cnt[i] = 0;

    bf16x8 bc = *(const bf16x8*)bptr;
#pragma unroll 2
    for (int t = 0; t < NT; t++) {
        const int tn = (t + 1) & (NT - 1);
        bf16x8 bn = *(const bf16x8*)(bptr + tn * 48 * 8);   // depth-1 prefetch
#pragma unroll
        for (int f = 0; f < RF; f++) {
            f32x4 acc = __builtin_amdgcn_mfma_f32_16x16x32_bf16(af[f], bc, zacc, 0, 0, 0);
            // sign-bit accumulate: adds -1 per NEGATIVE result (no vcc chain).
            cnt[f*4+0] += __float_as_int(acc[0]) >> 31;
            cnt[f*4+1] += __float_as_int(acc[1]) >> 31;
            cnt[f*4+2] += __float_as_int(acc[2]) >> 31;
            cnt[f*4+3] += __float_as_int(acc[3]) >> 31;
        }
        bc = bn;
    }

    // Sum across the 16 cols (lane bits 0..3); lane m==0 of each q adds rows.
    // Each row saw JW results total -> count_pos = JW + sum(negatives).
#pragma unroll
    for (int i = 0; i < 16; i++) {
        int v = cnt[i];
        v += __shfl_xor(v, 1);
        v += __shfl_xor(v, 2);
        v += __shfl_xor(v, 4);
        v += __shfl_xor(v, 8);
        cnt[i] = v;
    }
    if (m == 0) {
        int* ob = out + pbase + ibase + w * 64;
#pragma unroll
        for (int f = 0; f < RF; f++)
#pragma unroll
            for (int r = 0; r < 4; r++)
                atomicAdd(&ob[f*16 + q*4 + r], JW + cnt[f*4+r]);
    }
}

// ---------------- classify ----------------
__global__ __launch_bounds__(256)
void dbscan_classify(int* __restrict__ out) {
    const int p = blockIdx.x * 256 + threadIdx.x;
    out[p] = (out[p] < MIN_PTS) ? -1 : 0;
}

extern "C" void kernel_launch(void* const* d_in, const int* in_sizes, int n_in,
                              void* d_out, int out_size, void* d_ws, size_t ws_size,
                              hipStream_t stream) {
    const float* x = (const float*)d_in[0];
    int* out = (int*)d_out;
    __bf16* aug = (__bf16*)d_ws;   // 32768 * 48 B = 1.5 MB (+16 B overread pad)

    dbscan_prep<<<dim3(Bb * Np / 256), dim3(256), 0, stream>>>(x, aug, out);
    dbscan_count<<<dim3(Bb * 32 * JS), dim3(256), 0, stream>>>(aug, out);
    dbscan_classify<<<dim3(Bb * Np / 256), dim3(256), 0, stream>>>(out);
}